// Round 5
// baseline (301.775 us; speedup 1.0000x reference)
//
#include <hip/hip_runtime.h>

typedef _Float16 f16;
typedef _Float16 f16x4 __attribute__((ext_vector_type(4)));
typedef _Float16 f16x8 __attribute__((ext_vector_type(8)));
typedef float    fx4   __attribute__((ext_vector_type(4)));

#define MODE_PROJ   0
#define MODE_SCORES 1
#define MODE_PV     2

constexpr int Bsz = 4;
constexpr int S   = 2048;
constexpr int DK  = 1024;
constexpr int BM = 128, BN = 128, BK = 64;
constexpr long SD   = (long)S * DK;          // 2M elems
constexpr long SS   = (long)S * S;           // 4M elems
constexpr long BIGN = (long)Bsz * S * DK;    // 8M elems

// async global->LDS, 16B per lane; LDS dest wave-uniform (HW adds lane*16)
__device__ __forceinline__ void glds16(const f16* g, f16* l) {
    __builtin_amdgcn_global_load_lds(
        (const __attribute__((address_space(1))) void*)g,
        (__attribute__((address_space(3))) void*)l, 16, 0, 0);
}

// pair-packed f16 layout: f16 idx = (r>>1)<<SH | (r&1)<<10 | c
//   SH=12: gapped (in-place over fp32 buffer, region stride 8192 B)
//   SH=11: dense  (== r*1024 + c, workspace copy)
template<int SH>
__device__ __forceinline__ size_t pp(int r, int c) {
    return ((size_t)(r >> 1) << SH) + ((r & 1) << 10) + c;
}

// fp32 -> f16 pair-packed conversion. 3456 blocks x 4 chunks. Blocks 0..7
// additionally zero rowsum (replaces the separate memset dispatch).
__global__ __launch_bounds__(256)
void convert_kernel(const float* q, const float* k, const float* v,
                    const float* wq, const float* wk, const float* wv,
                    f16* dq, f16* dk, f16* dv,
                    f16* dwq, f16* dwk, f16* dwv,
                    int sh, int inplace, float* rowsum)
{
    const int tid = threadIdx.x;
    if (blockIdx.x < 8) {
        float4 zz = {0.f, 0.f, 0.f, 0.f};
        *(float4*)&rowsum[(blockIdx.x * 256 + tid) * 4] = zz;
    }
    float4 f0[4], f1[4];
    f16* dst[4];
    size_t doff[4];
    #pragma unroll
    for (int i = 0; i < 4; ++i) {
        int cx = blockIdx.x + i * 3456;
        const float* s; f16* d; int blk;
        if (cx < 12288) {
            int t = cx >> 12; blk = cx & 4095;
            s = (t == 0) ? q : (t == 1) ? k : v;
            d = (t == 0) ? dq : (t == 1) ? dk : dv;
        } else {
            int u = cx - 12288;
            int t = u >> 9; blk = u & 511;
            s = (t == 0) ? wq : (t == 1) ? wk : wv;
            d = (t == 0) ? dwq : (t == 1) ? dwk : dwv;
        }
        size_t off = (size_t)blk * 2048 + (size_t)tid * 8;
        f0[i] = *(const float4*)(s + off);
        f1[i] = *(const float4*)(s + off + 4);
        dst[i]  = d;
        doff[i] = ((size_t)blk << (sh + 1)) + (size_t)tid * 16;
    }
    if (inplace) __syncthreads();   // uniform branch; RMW hazard only in-place
    #pragma unroll
    for (int i = 0; i < 4; ++i) {
        f16x8 h = {(f16)f0[i].x, (f16)f0[i].y, (f16)f0[i].z, (f16)f0[i].w,
                   (f16)f1[i].x, (f16)f1[i].y, (f16)f1[i].z, (f16)f1[i].w};
        *(f16x8*)((char*)dst[i] + doff[i]) = h;
    }
}

// NT GEMM, fp16, glds16 staging with XOR bank swizzle, 128x128x64 tiles.
// (R0 structure, proven; 8-phase/256^2 restructures all regressed at
//  1 block/CU -- rounds 1-3. Do not re-attempt without new evidence.)
// zz >= 0 overrides blockIdx.y (lets proj z-slices launch as separate
// dispatches so scores/PV/convert surface in the top-5 counter window).
template<int MODE, int SH>
__global__ __launch_bounds__(256, 4)
void gemm_kernel(const f16* A0, const f16* A1, const f16* A2,
                 const f16* B0, const f16* B1, const f16* B2,
                 void* O0, void* O1, float* rowsum,
                 int lda, int ldb, int K, int ldo, int zz)
{
    __shared__ f16 lA[BM * BK];   // 16 KB
    __shared__ f16 lB[BN * BK];   // 16 KB

    const int tid = threadIdx.x;
    const int id  = blockIdx.x;
    const int z   = (zz >= 0) ? zz : (int)blockIdx.y;
    int row0, col0;
    if constexpr (MODE == MODE_PROJ) { row0 = (id & 63) * BM; col0 = (id >> 6) * BN; }
    else                             { row0 = (id & 15) * BM; col0 = (id >> 4) * BN; }

    const int lane = tid & 63;
    const int quad = lane >> 4;
    const int cn   = lane & 15;
    const int w    = tid >> 6;
    const int wm   = w >> 1;
    const int wn   = w & 1;

    const f16 *Ap, *Bp;
    if constexpr (MODE == MODE_PROJ) {
        Ap = (z == 0) ? A0 : (z == 1) ? A1 : A2;
        Bp = (z == 0) ? B0 : (z == 1) ? B1 : B2;
    } else if constexpr (MODE == MODE_SCORES) {
        Ap = A0 + (long)z * SD;  Bp = B0 + (long)z * SD;
        rowsum += (long)z * S;
    } else {
        Ap = A0 + (long)z * SS;  Bp = B0 + (long)z * SD;
        rowsum += (long)z * S;
    }

    fx4 acc[4][4];
    #pragma unroll
    for (int mt = 0; mt < 4; ++mt)
        #pragma unroll
        for (int nt = 0; nt < 4; ++nt)
            acc[mt][nt] = (fx4){0.f, 0.f, 0.f, 0.f};

    // staging lane map: 8 rows x 8 chunks of 16B; fetch XOR-permuted chunk so
    // LDS physical chunk (lane&7) holds global chunk (lane&7)^(row&7)
    const int lr8 = lane >> 3;            // 0..7 row within 8-row group
    const int swc = (lane & 7) ^ lr8;     // swizzled global chunk
    const int lcS = swc << 3;             // f16 col within BK

    for (int k0 = 0; k0 < K; k0 += BK) {
        __syncthreads();
        #pragma unroll
        for (int i = 0; i < 4; ++i) {
            int rb = w * 32 + i * 8;      // wave-uniform row base
            if constexpr (MODE == MODE_PROJ) {
                glds16(Ap + pp<SH>(row0 + rb + lr8, k0 + lcS), &lA[rb * BK]);
                glds16(Bp + pp<SH>(col0 + rb + lr8, k0 + lcS), &lB[rb * BK]);
            } else {
                glds16(Ap + (size_t)(row0 + rb + lr8) * lda + k0 + lcS, &lA[rb * BK]);
                glds16(Bp + (size_t)(col0 + rb + lr8) * ldb + k0 + lcS, &lB[rb * BK]);
            }
        }
        __syncthreads();

        #pragma unroll
        for (int kh = 0; kh < 2; ++kh) {
            f16x8 af[4], bf[4];
            #pragma unroll
            for (int mt = 0; mt < 4; ++mt) {
                int r = wm * 64 + mt * 16 + cn;
                int ch = ((kh << 2) | quad) ^ (r & 7);
                af[mt] = *(const f16x8*)&lA[r * BK + ch * 8];
            }
            #pragma unroll
            for (int nt = 0; nt < 4; ++nt) {
                int r = wn * 64 + nt * 16 + cn;
                int ch = ((kh << 2) | quad) ^ (r & 7);
                bf[nt] = *(const f16x8*)&lB[r * BK + ch * 8];
            }
            #pragma unroll
            for (int mt = 0; mt < 4; ++mt)
                #pragma unroll
                for (int nt = 0; nt < 4; ++nt)
                    acc[mt][nt] = __builtin_amdgcn_mfma_f32_16x16x32_f16(
                        af[mt], bf[nt], acc[mt][nt], 0, 0, 0);
        }
    }

    // C/D layout: col = lane&15, row = quad*4 + reg
    if constexpr (MODE == MODE_PROJ) {
        if (z < 2) {
            f16* O = (f16*)O0 + (long)z * BIGN;   // qp / kp
            #pragma unroll
            for (int mt = 0; mt < 4; ++mt) {
                int r0 = row0 + wm * 64 + mt * 16 + quad * 4;
                #pragma unroll
                for (int nt = 0; nt < 4; ++nt) {
                    int c = col0 + wn * 64 + nt * 16 + cn;
                    #pragma unroll
                    for (int reg = 0; reg < 4; ++reg)
                        O[(size_t)(r0 + reg) * DK + c] = (f16)acc[mt][nt][reg];
                }
            }
        } else {
            // v: transposed store -> vpT[b][e][s]
            #pragma unroll
            for (int mt = 0; mt < 4; ++mt) {
                int r0 = row0 + wm * 64 + mt * 16 + quad * 4;
                int b  = r0 >> 11;
                int s  = r0 & 2047;
                f16* O = (f16*)O1 + (long)b * SD;
                #pragma unroll
                for (int nt = 0; nt < 4; ++nt) {
                    int c = col0 + wn * 64 + nt * 16 + cn;
                    f16x4 h = {(f16)acc[mt][nt][0], (f16)acc[mt][nt][1],
                               (f16)acc[mt][nt][2], (f16)acc[mt][nt][3]};
                    *(f16x4*)&O[(size_t)c * S + s] = h;
                }
            }
        }
    } else if constexpr (MODE == MODE_SCORES) {
        f16* O = (f16*)O0 + (long)z * SS;
        const float sl2e = 0.03125f * 1.44269504f;  // (1/32)*log2(e)
        float rs[4][4];
        #pragma unroll
        for (int mt = 0; mt < 4; ++mt)
            #pragma unroll
            for (int reg = 0; reg < 4; ++reg) rs[mt][reg] = 0.f;
        #pragma unroll
        for (int mt = 0; mt < 4; ++mt) {
            int r0 = row0 + wm * 64 + mt * 16 + quad * 4;
            #pragma unroll
            for (int nt = 0; nt < 4; ++nt) {
                int c = col0 + wn * 64 + nt * 16 + cn;
                #pragma unroll
                for (int reg = 0; reg < 4; ++reg) {
                    float vv = exp2f(acc[mt][nt][reg] * sl2e);
                    rs[mt][reg] += vv;
                    O[(size_t)(r0 + reg) * ldo + c] = (f16)vv;
                }
            }
        }
        #pragma unroll
        for (int mt = 0; mt < 4; ++mt) {
            int r0 = row0 + wm * 64 + mt * 16 + quad * 4;
            #pragma unroll
            for (int reg = 0; reg < 4; ++reg) {
                float vv = rs[mt][reg];
                vv += __shfl_xor(vv, 1);
                vv += __shfl_xor(vv, 2);
                vv += __shfl_xor(vv, 4);
                vv += __shfl_xor(vv, 8);
                if (cn == 0) atomicAdd(&rowsum[r0 + reg], vv);
            }
        }
    } else {  // MODE_PV
        float* O = (float*)O0 + (long)z * SD;
        #pragma unroll
        for (int mt = 0; mt < 4; ++mt) {
            int r0 = row0 + wm * 64 + mt * 16 + quad * 4;
            fx4 rsv = *(const fx4*)&rowsum[r0];
            fx4 inv = {1.f / rsv[0], 1.f / rsv[1], 1.f / rsv[2], 1.f / rsv[3]};
            #pragma unroll
            for (int nt = 0; nt < 4; ++nt) {
                int c = col0 + wn * 64 + nt * 16 + cn;
                #pragma unroll
                for (int reg = 0; reg < 4; ++reg)
                    O[(size_t)(r0 + reg) * ldo + c] = acc[mt][nt][reg] * inv[reg];
            }
        }
    }
}

extern "C" void kernel_launch(void* const* d_in, const int* in_sizes, int n_in,
                              void* d_out, int out_size, void* d_ws, size_t ws_size,
                              hipStream_t stream) {
    const float* q  = (const float*)d_in[0];
    const float* k  = (const float*)d_in[1];
    const float* v  = (const float*)d_in[2];
    const float* wq = (const float*)d_in[3];
    const float* wk = (const float*)d_in[4];
    const float* wv = (const float*)d_in[5];
    float* out = (float*)d_out;

    char* ws = (char*)d_ws;
    f16*   qp     = (f16*)(ws);                          // 16 MB [8192, 1024]
    f16*   kp     = (f16*)(ws + ((size_t)16 << 20));     // 16 MB [8192, 1024]
    f16*   vpT    = (f16*)(ws + ((size_t)32 << 20));     // 16 MB [B][DK][S]
    f16*   E      = (f16*)(ws + ((size_t)48 << 20));     // 32 MB [B][S][S]
    float* rowsum = (float*)(ws + ((size_t)80 << 20));   // 32 KB [B][S]

    // f16 input copies (dense pair-packed) at 81 MiB when ws permits;
    // otherwise fall back to the proven in-place (gapped) conversion.
    const bool usews = ws_size >= ((size_t)135 << 20);
    char* cb = ws + ((size_t)81 << 20);
    f16 *dq, *dk, *dv, *dwq, *dwk, *dwv;
    if (usews) {
        dq  = (f16*)(cb);
        dk  = (f16*)(cb + ((size_t)16 << 20));
        dv  = (f16*)(cb + ((size_t)32 << 20));
        dwq = (f16*)(cb + ((size_t)48 << 20));
        dwk = (f16*)(cb + ((size_t)50 << 20));
        dwv = (f16*)(cb + ((size_t)52 << 20));
    } else {
        dq  = (f16*)q;  dk  = (f16*)k;  dv  = (f16*)v;
        dwq = (f16*)wq; dwk = (f16*)wk; dwv = (f16*)wv;
    }

    convert_kernel<<<3456, 256, 0, stream>>>(
        q, k, v, wq, wk, wv, dq, dk, dv, dwq, dwk, dwv,
        usews ? 11 : 12, usews ? 0 : 1, rowsum);

    dim3 blk(256);
    // projections, one dispatch per z-slice (math identical to the fused
    // dim3(512,3) launch; zz overrides blockIdx.y). Purpose: each slice is
    // ~20 us, so scores/PV/convert surface in the top-5 counter window.
    if (usews) {
        gemm_kernel<MODE_PROJ, 11><<<512, blk, 0, stream>>>(
            dq, dk, dv, dwq, dwk, dwv, qp, vpT, nullptr, DK, DK, DK, DK, 0);
        gemm_kernel<MODE_PROJ, 11><<<512, blk, 0, stream>>>(
            dq, dk, dv, dwq, dwk, dwv, qp, vpT, nullptr, DK, DK, DK, DK, 1);
        gemm_kernel<MODE_PROJ, 11><<<512, blk, 0, stream>>>(
            dq, dk, dv, dwq, dwk, dwv, qp, vpT, nullptr, DK, DK, DK, DK, 2);
    } else {
        gemm_kernel<MODE_PROJ, 12><<<512, blk, 0, stream>>>(
            dq, dk, dv, dwq, dwk, dwv, qp, vpT, nullptr, DK, DK, DK, DK, 0);
        gemm_kernel<MODE_PROJ, 12><<<512, blk, 0, stream>>>(
            dq, dk, dv, dwq, dwk, dwv, qp, vpT, nullptr, DK, DK, DK, DK, 1);
        gemm_kernel<MODE_PROJ, 12><<<512, blk, 0, stream>>>(
            dq, dk, dv, dwq, dwk, dwv, qp, vpT, nullptr, DK, DK, DK, DK, 2);
    }
    // scores: E = exp(qp.kp/32), rowsum accumulated
    gemm_kernel<MODE_SCORES, 12><<<dim3(256, 4), blk, 0, stream>>>(
        qp, nullptr, nullptr, kp, nullptr, nullptr, E, nullptr, rowsum,
        DK, DK, DK, S, -1);
    // PV: out = (E @ vpT^T) / rowsum
    gemm_kernel<MODE_PV, 12><<<dim3(128, 4), blk, 0, stream>>>(
        E, nullptr, nullptr, vpT, nullptr, nullptr, out, nullptr, rowsum,
        S, S, S, DK, -1);
}